// Round 6
// baseline (230.019 us; speedup 1.0000x reference)
//
#include <hip/hip_runtime.h>

// VIN forward — R6 DIAGNOSTIC ROUND.
// Real pipeline (VI<10> + MLP) unchanged from R5. Appended: four dead-output
// VI diagnostic dispatches into deep d_ws scratch, sized to exceed the ~40us
// harness fill dispatches so they surface in the rocprof top-5 with counters:
//   VI<25,true>, VI<37,true>, VI<49,true>  -> per-iteration cost slope
//   VI<49,false>                           -> boundary-exchange/barrier ablated
// All instances share one body (#pragma unroll 1 on the iter loop) so codegen
// is comparable; real output is unaffected (diags write dead scratch).

#define K_ITERS 10

// lane i <- lane i-1 (column l-1), lane 0 <- 0.0f  (wave_shr:1, bound_ctrl:1)
__device__ __forceinline__ float shr1(float x) {
#if __has_builtin(__builtin_amdgcn_mov_dpp)
    return __int_as_float(__builtin_amdgcn_mov_dpp(__float_as_int(x), 0x138, 0xF, 0xF, true));
#else
    return __int_as_float(__builtin_amdgcn_update_dpp(0, __float_as_int(x), 0x138, 0xF, 0xF, true));
#endif
}
// lane i <- lane i+1 (column l+1), lane 63 <- 0.0f  (wave_shl:1, bound_ctrl:1)
__device__ __forceinline__ float shl1(float x) {
#if __has_builtin(__builtin_amdgcn_mov_dpp)
    return __int_as_float(__builtin_amdgcn_mov_dpp(__float_as_int(x), 0x130, 0xF, 0xF, true));
#else
    return __int_as_float(__builtin_amdgcn_update_dpp(0, __float_as_int(x), 0x130, 0xF, 0xF, true));
#endif
}

template<int KITERS, bool EXCH>
__global__ __launch_bounds__(512, 4) void vin_vi_kernel(
    const float* __restrict__ obs,     // [B,64,64,3]
    const float* __restrict__ W_phi,   // [3,3]
    const float* __restrict__ b_phi,   // [3]
    float* __restrict__ feats_out)     // [B,36]
{
    const int b   = blockIdx.x;
    const int tid = threadIdx.x;
    const int w   = tid >> 6;   // wave id 0..7: rows 8w .. 8w+7
    const int l   = tid & 63;   // lane = column

    __shared__ float v_s[64 * 64];       // 16 KB (final value map, gather only)
    __shared__ float bnd[2][2][8][64];   // 8 KB: v boundary rows
    __shared__ float rbnd[2][8][64];     // 2 KB: rin boundary rows (static)
    __shared__ int   agent_pos;

    const float* ob = obs + (size_t)b * (4096 * 3);

    const float w00 = W_phi[0], w01 = W_phi[1], w02 = W_phi[2];
    const float w10 = W_phi[3], w11 = W_phi[4], w12 = W_phi[5];
    const float w20 = W_phi[6], w21 = W_phi[7], w22 = W_phi[8];
    const float bp0 = b_phi[0], bp1 = b_phi[1], bp2 = b_phi[2];

    float p[8], rin[8], rout[8];

    #pragma unroll
    for (int k = 0; k < 8; ++k) {
        const int cell = (8 * w + k) * 64 + l;
        const float o0 = ob[cell * 3 + 0];
        const float o1 = ob[cell * 3 + 1];
        const float o2 = ob[cell * 3 + 2];
        p[k]    = fmaxf(fmaf(o2, w20, fmaf(o1, w10, fmaf(o0, w00, bp0))), 0.f);
        rin[k]  = fmaxf(fmaf(o2, w21, fmaf(o1, w11, fmaf(o0, w01, bp1))), 0.f);
        rout[k] = fmaxf(fmaf(o2, w22, fmaf(o1, w12, fmaf(o0, w02, bp2))), 0.f);
        if (o1 > 0.5f) agent_pos = cell;   // one-hot agent: single writer
    }

    // Static rin boundary rows (rows 8w-1 / 8w+8), once.
    rbnd[0][w][l] = rin[0];
    rbnd[1][w][l] = rin[7];
    __syncthreads();
    const float rinU_b = (w > 0) ? rbnd[1][w - 1][l] : 0.f;
    const float rinD_b = (w < 7) ? rbnd[0][w + 1][l] : 0.f;

    // aX[k] = rin(neighbor X) - rout[k]; out-of-grid terms = -rout <= 0 never
    // win the max (v >= 0 monotone, p/rin/rout >= 0, DPP zero-fill at edges).
    float aU[8], aD[8], aL[8], aR[8], v[8];
    #pragma unroll
    for (int k = 0; k < 8; ++k) {
        aU[k] = ((k > 0) ? rin[k - 1] : rinU_b) - rout[k];
        aD[k] = ((k < 7) ? rin[k + 1] : rinD_b) - rout[k];
        aL[k] = shr1(rin[k]) - rout[k];
        aR[k] = shl1(rin[k]) - rout[k];
    }

    // Iter 0 peeled: v==0 everywhere.
    #pragma unroll
    for (int k = 0; k < 8; ++k)
        v[k] = fmaxf(0.f, fmaxf(fmaxf(aU[k], aD[k]), fmaxf(aL[k], aR[k])));
    if (EXCH) {
        bnd[0][0][w][l] = v[0];
        bnd[0][1][w][l] = v[7];
    }

    #pragma unroll 1
    for (int it = 1; it < KITERS; ++it) {
        const int rd = (it - 1) & 1, wr = it & 1;
        float vU_b = 0.f, vD_b = 0.f;
        if (EXCH) {
            __syncthreads();
            vU_b = (w > 0) ? bnd[rd][1][w - 1][l] : 0.f;
            vD_b = (w < 7) ? bnd[rd][0][w + 1][l] : 0.f;
        }

        const float ov7 = v[7];
        {   // k = 7 first (uses old v[6], vD_b); store boundary early.
            const float vk = ov7;
            const float vL = shr1(vk), vR = shl1(vk);
            const float tU = fmaf(p[7], v[6], aU[7]);
            const float tD = fmaf(p[7], vD_b, aD[7]);
            const float tL = fmaf(p[7], vL, aL[7]);
            const float tR = fmaf(p[7], vR, aR[7]);
            v[7] = fmaxf(vk, fmaxf(fmaxf(tU, tD), fmaxf(tL, tR)));
            if (EXCH) bnd[wr][1][w][l] = v[7];
        }
        const float ov0 = v[0];
        {   // k = 0 (uses vU_b, old v[1]); store boundary early.
            const float vk = ov0;
            const float vL = shr1(vk), vR = shl1(vk);
            const float tU = fmaf(p[0], vU_b, aU[0]);
            const float tD = fmaf(p[0], v[1], aD[0]);
            const float tL = fmaf(p[0], vL, aL[0]);
            const float tR = fmaf(p[0], vR, aR[0]);
            v[0] = fmaxf(vk, fmaxf(fmaxf(tU, tD), fmaxf(tL, tR)));
            if (EXCH) bnd[wr][0][w][l] = v[0];
        }
        float vm1 = ov0;   // old previous-row value (Jacobi)
        #pragma unroll
        for (int k = 1; k < 7; ++k) {
            const float vk  = v[k];
            const float vp1 = (k < 6) ? v[k + 1] : ov7;
            const float vL  = shr1(vk), vR = shl1(vk);
            const float tU  = fmaf(p[k], vm1, aU[k]);
            const float tD  = fmaf(p[k], vp1, aD[k]);
            const float tL  = fmaf(p[k], vL, aL[k]);
            const float tR  = fmaf(p[k], vR, aR[k]);
            v[k] = fmaxf(vk, fmaxf(fmaxf(tU, tD), fmaxf(tL, tR)));
            vm1 = vk;
        }
    }

    #pragma unroll
    for (int k = 0; k < 8; ++k) v_s[(8 * w + k) * 64 + l] = v[k];
    __syncthreads();

    // 36 features: 3x3 zero-padded windows of (1-walls), agent, goal, v.
    if (tid < 36) {
        const int ap = agent_pos;
        const int ar = ap >> 6, ac = ap & 63;
        const int g  = tid / 9, o = tid % 9;
        const int rr = ar + o / 3 - 1;
        const int cc = ac + o % 3 - 1;
        float val = 0.f;
        if (rr >= 0 && rr < 64 && cc >= 0 && cc < 64) {
            const int cell = rr * 64 + cc;
            if      (g == 0) val = 1.f - ob[cell * 3 + 0];
            else if (g == 1) val = ob[cell * 3 + 1];
            else if (g == 2) val = ob[cell * 3 + 2];
            else             val = v_s[cell];
        }
        feats_out[b * 36 + tid] = val;
    }
}

__global__ __launch_bounds__(1024) void vin_mlp_kernel(
    const float* __restrict__ feats,   // [B,36]
    const float* __restrict__ W1,      // [36,256]
    const float* __restrict__ b1,      // [256]
    const float* __restrict__ W2,      // [256,256]
    const float* __restrict__ b2,      // [256]
    const float* __restrict__ Wl,      // [256,5]
    const float* __restrict__ bl,      // [5]
    float* __restrict__ out)           // [B,5]
{
    const int b0  = blockIdx.x * 4;    // 4 samples per block
    const int tid = threadIdx.x;
    const int c   = tid & 255;         // output column
    const int q   = tid >> 8;          // K-quarter 0..3

    __shared__ float f_s[4][36];
    __shared__ float part[4][4][256];              // [quarter][sample][col] 16KB
    __shared__ __align__(16) float h1_s[256][4];   // [col][sample] 4KB
    __shared__ __align__(16) float h2_s[4][256];   // 4KB
    __shared__ float red[16][4][5];                // 1.25KB

    if (tid < 144) f_s[tid / 36][tid % 36] = feats[b0 * 36 + tid];
    __syncthreads();

    // 36 -> 256 (linear), split-K: quarter q sums rows [9q, 9q+9)
    {
        float a0 = 0.f, a1 = 0.f, a2 = 0.f, a3 = 0.f;
        #pragma unroll
        for (int m = 0; m < 9; ++m) {
            const int i = 9 * q + m;
            const float wv = W1[i * 256 + c];
            a0 = fmaf(f_s[0][i], wv, a0);
            a1 = fmaf(f_s[1][i], wv, a1);
            a2 = fmaf(f_s[2][i], wv, a2);
            a3 = fmaf(f_s[3][i], wv, a3);
        }
        part[q][0][c] = a0; part[q][1][c] = a1;
        part[q][2][c] = a2; part[q][3][c] = a3;
    }
    __syncthreads();
    h1_s[c][q] = b1[c] + ((part[0][q][c] + part[1][q][c]) +
                          (part[2][q][c] + part[3][q][c]));
    __syncthreads();

    // 256 -> 256 (linear), split-K: quarter q sums rows [64q, 64q+64)
    {
        float a0 = 0.f, a1 = 0.f, a2 = 0.f, a3 = 0.f;
        #pragma unroll 8
        for (int m = 0; m < 64; ++m) {
            const int i = 64 * q + m;
            const float wv = W2[i * 256 + c];
            const float4 hv = *reinterpret_cast<const float4*>(&h1_s[i][0]); // bcast
            a0 = fmaf(hv.x, wv, a0);
            a1 = fmaf(hv.y, wv, a1);
            a2 = fmaf(hv.z, wv, a2);
            a3 = fmaf(hv.w, wv, a3);
        }
        part[q][0][c] = a0; part[q][1][c] = a1;
        part[q][2][c] = a2; part[q][3][c] = a3;
    }
    __syncthreads();
    h2_s[q][c] = b2[c] + ((part[0][q][c] + part[1][q][c]) +
                          (part[2][q][c] + part[3][q][c]));
    __syncthreads();

    // 256 -> 5: 320 threads, each sums a 16-wide chunk for one (sample,logit)
    if (tid < 320) {
        const int s  = tid & 3;
        const int j  = (tid >> 2) % 5;
        const int ch = tid / 20;        // 0..15
        float acc = 0.f;
        #pragma unroll
        for (int m = 0; m < 16; ++m) {
            const int i = ch * 16 + m;
            acc = fmaf(h2_s[s][i], Wl[i * 5 + j], acc);
        }
        red[ch][s][j] = acc;
    }
    __syncthreads();
    if (tid < 20) {
        const int s = tid & 3;
        const int j = tid >> 2;
        float o = bl[j];
        #pragma unroll
        for (int ch = 0; ch < 16; ++ch) o += red[ch][s][j];
        out[(b0 + s) * 5 + j] = o;
    }
}

extern "C" void kernel_launch(void* const* d_in, const int* in_sizes, int n_in,
                              void* d_out, int out_size, void* d_ws, size_t ws_size,
                              hipStream_t stream) {
    const float* obs   = (const float*)d_in[0];
    const float* W_phi = (const float*)d_in[1];
    const float* b_phi = (const float*)d_in[2];
    const float* W1    = (const float*)d_in[3];
    const float* b1    = (const float*)d_in[4];
    const float* W2    = (const float*)d_in[5];
    const float* b2    = (const float*)d_in[6];
    const float* Wl    = (const float*)d_in[7];
    const float* bl    = (const float*)d_in[8];
    float* out   = (float*)d_out;
    float* feats = (float*)d_ws;   // 1024*36*4 = 147456 bytes

    // Real pipeline (graph-validated output path).
    vin_vi_kernel<K_ITERS, true><<<dim3(1024), dim3(512), 0, stream>>>(obs, W_phi, b_phi, feats);
    vin_mlp_kernel<<<dim3(256), dim3(1024), 0, stream>>>(feats, W1, b1, W2, b2, Wl, bl, out);

    // Diagnostics: dead-output VI variants, long enough (>40us) to surface in
    // the rocprof top-5 above the harness fill dispatches. Deterministic.
    if (ws_size >= (64u << 20)) {
        float* dg = (float*)((char*)d_ws + (32u << 20));
        vin_vi_kernel<25, true ><<<dim3(1024), dim3(512), 0, stream>>>(obs, W_phi, b_phi, dg);
        vin_vi_kernel<37, true ><<<dim3(1024), dim3(512), 0, stream>>>(obs, W_phi, b_phi, dg + 40960);
        vin_vi_kernel<49, true ><<<dim3(1024), dim3(512), 0, stream>>>(obs, W_phi, b_phi, dg + 81920);
        vin_vi_kernel<49, false><<<dim3(1024), dim3(512), 0, stream>>>(obs, W_phi, b_phi, dg + 122880);
    }
}

// Round 7
// 140.756 us; speedup vs baseline: 1.6342x; 1.6342x over previous
//
#include <hip/hip_runtime.h>

// VIN forward — R7: fix register allocation.
// R6 diagnostics showed VGPR_Count=32 for a loop with >=48 live floats ->
// state was juggled through AGPRs/scratch (2x VALU bloat), and the EXCH
// ablation was null (barriers/LDS exchange free). The suspect is the
// __launch_bounds__ min-waves arg used since R2. This round: plain
// __launch_bounds__(512) so the allocator keeps state resident.
// One diagnostic dispatch (VI<97>) retained to verify new codegen counters;
// drop it next round.

#define K_ITERS 10

// lane i <- lane i-1 (column l-1), lane 0 <- 0.0f  (wave_shr:1, bound_ctrl:1)
__device__ __forceinline__ float shr1(float x) {
#if __has_builtin(__builtin_amdgcn_mov_dpp)
    return __int_as_float(__builtin_amdgcn_mov_dpp(__float_as_int(x), 0x138, 0xF, 0xF, true));
#else
    return __int_as_float(__builtin_amdgcn_update_dpp(0, __float_as_int(x), 0x138, 0xF, 0xF, true));
#endif
}
// lane i <- lane i+1 (column l+1), lane 63 <- 0.0f  (wave_shl:1, bound_ctrl:1)
__device__ __forceinline__ float shl1(float x) {
#if __has_builtin(__builtin_amdgcn_mov_dpp)
    return __int_as_float(__builtin_amdgcn_mov_dpp(__float_as_int(x), 0x130, 0xF, 0xF, true));
#else
    return __int_as_float(__builtin_amdgcn_update_dpp(0, __float_as_int(x), 0x130, 0xF, 0xF, true));
#endif
}

template<int KITERS>
__global__ __launch_bounds__(512) void vin_vi_kernel(
    const float* __restrict__ obs,     // [B,64,64,3]
    const float* __restrict__ W_phi,   // [3,3]
    const float* __restrict__ b_phi,   // [3]
    float* __restrict__ feats_out)     // [B,36]
{
    const int b   = blockIdx.x;
    const int tid = threadIdx.x;
    const int w   = tid >> 6;   // wave id 0..7: rows 8w .. 8w+7
    const int l   = tid & 63;   // lane = column

    __shared__ float v_s[64 * 64];       // 16 KB (final value map, gather only)
    __shared__ float bnd[2][2][8][64];   // 8 KB: v boundary rows
    __shared__ float rbnd[2][8][64];     // 2 KB: rin boundary rows (static)
    __shared__ int   agent_pos;

    const float* ob = obs + (size_t)b * (4096 * 3);

    const float w00 = W_phi[0], w01 = W_phi[1], w02 = W_phi[2];
    const float w10 = W_phi[3], w11 = W_phi[4], w12 = W_phi[5];
    const float w20 = W_phi[6], w21 = W_phi[7], w22 = W_phi[8];
    const float bp0 = b_phi[0], bp1 = b_phi[1], bp2 = b_phi[2];

    float p[8], rin[8], rout[8];

    #pragma unroll
    for (int k = 0; k < 8; ++k) {
        const int cell = (8 * w + k) * 64 + l;
        const float o0 = ob[cell * 3 + 0];
        const float o1 = ob[cell * 3 + 1];
        const float o2 = ob[cell * 3 + 2];
        p[k]    = fmaxf(fmaf(o2, w20, fmaf(o1, w10, fmaf(o0, w00, bp0))), 0.f);
        rin[k]  = fmaxf(fmaf(o2, w21, fmaf(o1, w11, fmaf(o0, w01, bp1))), 0.f);
        rout[k] = fmaxf(fmaf(o2, w22, fmaf(o1, w12, fmaf(o0, w02, bp2))), 0.f);
        if (o1 > 0.5f) agent_pos = cell;   // one-hot agent: single writer
    }

    // Static rin boundary rows (rows 8w-1 / 8w+8), once.
    rbnd[0][w][l] = rin[0];
    rbnd[1][w][l] = rin[7];
    __syncthreads();
    const float rinU_b = (w > 0) ? rbnd[1][w - 1][l] : 0.f;
    const float rinD_b = (w < 7) ? rbnd[0][w + 1][l] : 0.f;

    // aX[k] = rin(neighbor X) - rout[k]; out-of-grid terms = -rout <= 0 never
    // win the max (v >= 0 monotone, p/rin/rout >= 0, DPP zero-fill at edges).
    float aU[8], aD[8], aL[8], aR[8], v[8];
    #pragma unroll
    for (int k = 0; k < 8; ++k) {
        aU[k] = ((k > 0) ? rin[k - 1] : rinU_b) - rout[k];
        aD[k] = ((k < 7) ? rin[k + 1] : rinD_b) - rout[k];
        aL[k] = shr1(rin[k]) - rout[k];
        aR[k] = shl1(rin[k]) - rout[k];
    }

    // Iter 0 peeled: v==0 everywhere.
    #pragma unroll
    for (int k = 0; k < 8; ++k)
        v[k] = fmaxf(0.f, fmaxf(fmaxf(aU[k], aD[k]), fmaxf(aL[k], aR[k])));
    bnd[0][0][w][l] = v[0];
    bnd[0][1][w][l] = v[7];

    for (int it = 1; it < KITERS; ++it) {
        const int rd = (it - 1) & 1, wr = it & 1;
        __syncthreads();
        const float vU_b = (w > 0) ? bnd[rd][1][w - 1][l] : 0.f;
        const float vD_b = (w < 7) ? bnd[rd][0][w + 1][l] : 0.f;

        const float ov7 = v[7];
        {   // k = 7 first (uses old v[6], vD_b); store boundary early.
            const float vk = ov7;
            const float vL = shr1(vk), vR = shl1(vk);
            const float tU = fmaf(p[7], v[6], aU[7]);
            const float tD = fmaf(p[7], vD_b, aD[7]);
            const float tL = fmaf(p[7], vL, aL[7]);
            const float tR = fmaf(p[7], vR, aR[7]);
            v[7] = fmaxf(vk, fmaxf(fmaxf(tU, tD), fmaxf(tL, tR)));
            bnd[wr][1][w][l] = v[7];
        }
        const float ov0 = v[0];
        {   // k = 0 (uses vU_b, old v[1]); store boundary early.
            const float vk = ov0;
            const float vL = shr1(vk), vR = shl1(vk);
            const float tU = fmaf(p[0], vU_b, aU[0]);
            const float tD = fmaf(p[0], v[1], aD[0]);
            const float tL = fmaf(p[0], vL, aL[0]);
            const float tR = fmaf(p[0], vR, aR[0]);
            v[0] = fmaxf(vk, fmaxf(fmaxf(tU, tD), fmaxf(tL, tR)));
            bnd[wr][0][w][l] = v[0];
        }
        float vm1 = ov0;   // old previous-row value (Jacobi)
        #pragma unroll
        for (int k = 1; k < 7; ++k) {
            const float vk  = v[k];
            const float vp1 = (k < 6) ? v[k + 1] : ov7;
            const float vL  = shr1(vk), vR = shl1(vk);
            const float tU  = fmaf(p[k], vm1, aU[k]);
            const float tD  = fmaf(p[k], vp1, aD[k]);
            const float tL  = fmaf(p[k], vL, aL[k]);
            const float tR  = fmaf(p[k], vR, aR[k]);
            v[k] = fmaxf(vk, fmaxf(fmaxf(tU, tD), fmaxf(tL, tR)));
            vm1 = vk;
        }
    }

    #pragma unroll
    for (int k = 0; k < 8; ++k) v_s[(8 * w + k) * 64 + l] = v[k];
    __syncthreads();

    // 36 features: 3x3 zero-padded windows of (1-walls), agent, goal, v.
    if (tid < 36) {
        const int ap = agent_pos;
        const int ar = ap >> 6, ac = ap & 63;
        const int g  = tid / 9, o = tid % 9;
        const int rr = ar + o / 3 - 1;
        const int cc = ac + o % 3 - 1;
        float val = 0.f;
        if (rr >= 0 && rr < 64 && cc >= 0 && cc < 64) {
            const int cell = rr * 64 + cc;
            if      (g == 0) val = 1.f - ob[cell * 3 + 0];
            else if (g == 1) val = ob[cell * 3 + 1];
            else if (g == 2) val = ob[cell * 3 + 2];
            else             val = v_s[cell];
        }
        feats_out[b * 36 + tid] = val;
    }
}

__global__ __launch_bounds__(1024) void vin_mlp_kernel(
    const float* __restrict__ feats,   // [B,36]
    const float* __restrict__ W1,      // [36,256]
    const float* __restrict__ b1,      // [256]
    const float* __restrict__ W2,      // [256,256]
    const float* __restrict__ b2,      // [256]
    const float* __restrict__ Wl,      // [256,5]
    const float* __restrict__ bl,      // [5]
    float* __restrict__ out)           // [B,5]
{
    const int b0  = blockIdx.x * 4;    // 4 samples per block
    const int tid = threadIdx.x;
    const int c   = tid & 255;         // output column
    const int q   = tid >> 8;          // K-quarter 0..3

    __shared__ float f_s[4][36];
    __shared__ float part[4][4][256];              // [quarter][sample][col] 16KB
    __shared__ __align__(16) float h1_s[256][4];   // [col][sample] 4KB
    __shared__ __align__(16) float h2_s[4][256];   // 4KB
    __shared__ float red[16][4][5];                // 1.25KB

    if (tid < 144) f_s[tid / 36][tid % 36] = feats[b0 * 36 + tid];
    __syncthreads();

    // 36 -> 256 (linear), split-K: quarter q sums rows [9q, 9q+9)
    {
        float a0 = 0.f, a1 = 0.f, a2 = 0.f, a3 = 0.f;
        #pragma unroll
        for (int m = 0; m < 9; ++m) {
            const int i = 9 * q + m;
            const float wv = W1[i * 256 + c];
            a0 = fmaf(f_s[0][i], wv, a0);
            a1 = fmaf(f_s[1][i], wv, a1);
            a2 = fmaf(f_s[2][i], wv, a2);
            a3 = fmaf(f_s[3][i], wv, a3);
        }
        part[q][0][c] = a0; part[q][1][c] = a1;
        part[q][2][c] = a2; part[q][3][c] = a3;
    }
    __syncthreads();
    h1_s[c][q] = b1[c] + ((part[0][q][c] + part[1][q][c]) +
                          (part[2][q][c] + part[3][q][c]));
    __syncthreads();

    // 256 -> 256 (linear), split-K: quarter q sums rows [64q, 64q+64)
    {
        float a0 = 0.f, a1 = 0.f, a2 = 0.f, a3 = 0.f;
        #pragma unroll 8
        for (int m = 0; m < 64; ++m) {
            const int i = 64 * q + m;
            const float wv = W2[i * 256 + c];
            const float4 hv = *reinterpret_cast<const float4*>(&h1_s[i][0]); // bcast
            a0 = fmaf(hv.x, wv, a0);
            a1 = fmaf(hv.y, wv, a1);
            a2 = fmaf(hv.z, wv, a2);
            a3 = fmaf(hv.w, wv, a3);
        }
        part[q][0][c] = a0; part[q][1][c] = a1;
        part[q][2][c] = a2; part[q][3][c] = a3;
    }
    __syncthreads();
    h2_s[q][c] = b2[c] + ((part[0][q][c] + part[1][q][c]) +
                          (part[2][q][c] + part[3][q][c]));
    __syncthreads();

    // 256 -> 5: 320 threads, each sums a 16-wide chunk for one (sample,logit)
    if (tid < 320) {
        const int s  = tid & 3;
        const int j  = (tid >> 2) % 5;
        const int ch = tid / 20;        // 0..15
        float acc = 0.f;
        #pragma unroll
        for (int m = 0; m < 16; ++m) {
            const int i = ch * 16 + m;
            acc = fmaf(h2_s[s][i], Wl[i * 5 + j], acc);
        }
        red[ch][s][j] = acc;
    }
    __syncthreads();
    if (tid < 20) {
        const int s = tid & 3;
        const int j = tid >> 2;
        float o = bl[j];
        #pragma unroll
        for (int ch = 0; ch < 16; ++ch) o += red[ch][s][j];
        out[(b0 + s) * 5 + j] = o;
    }
}

extern "C" void kernel_launch(void* const* d_in, const int* in_sizes, int n_in,
                              void* d_out, int out_size, void* d_ws, size_t ws_size,
                              hipStream_t stream) {
    const float* obs   = (const float*)d_in[0];
    const float* W_phi = (const float*)d_in[1];
    const float* b_phi = (const float*)d_in[2];
    const float* W1    = (const float*)d_in[3];
    const float* b1    = (const float*)d_in[4];
    const float* W2    = (const float*)d_in[5];
    const float* b2    = (const float*)d_in[6];
    const float* Wl    = (const float*)d_in[7];
    const float* bl    = (const float*)d_in[8];
    float* out   = (float*)d_out;
    float* feats = (float*)d_ws;   // 1024*36*4 = 147456 bytes

    // Real pipeline.
    vin_vi_kernel<K_ITERS><<<dim3(1024), dim3(512), 0, stream>>>(obs, W_phi, b_phi, feats);
    vin_mlp_kernel<<<dim3(256), dim3(1024), 0, stream>>>(feats, W1, b1, W2, b2, Wl, bl, out);

    // Single diagnostic (dead output, deep scratch): long enough to surface in
    // rocprof top-5 above the ~40us harness fills; verifies new codegen.
    if (ws_size >= (64u << 20)) {
        float* dg = (float*)((char*)d_ws + (32u << 20));
        vin_vi_kernel<97><<<dim3(1024), dim3(512), 0, stream>>>(obs, W_phi, b_phi, dg);
    }
}

// Round 8
// 133.398 us; speedup vs baseline: 1.7243x; 1.0552x over previous
//
#include <hip/hip_runtime.h>

// VIN forward — R8: shrink per-thread state so register allocation can't hurt.
// R7 showed VI slope 1.15us/iter with ~1.6x VALU bloat (VGPR_Count=32 vs 48+
// live floats -> arch/AGPR juggling). New VI structure: block=1024, 16 waves,
// wave w owns rows [4w,4w+4) -> 24 live floats/thread. Same algorithm:
// DPP wave shifts for columns, register k+-1 for rows, LDS for the 2 boundary
// rows per wave, folded (rin_nb - rout) direction constants, iter-0 peeled.
// One diagnostic VI<97> retained for counters (dead output, deep scratch).

#define K_ITERS 10

// lane i <- lane i-1 (column l-1), lane 0 <- 0.0f  (wave_shr:1, bound_ctrl:1)
__device__ __forceinline__ float shr1(float x) {
#if __has_builtin(__builtin_amdgcn_mov_dpp)
    return __int_as_float(__builtin_amdgcn_mov_dpp(__float_as_int(x), 0x138, 0xF, 0xF, true));
#else
    return __int_as_float(__builtin_amdgcn_update_dpp(0, __float_as_int(x), 0x138, 0xF, 0xF, true));
#endif
}
// lane i <- lane i+1 (column l+1), lane 63 <- 0.0f  (wave_shl:1, bound_ctrl:1)
__device__ __forceinline__ float shl1(float x) {
#if __has_builtin(__builtin_amdgcn_mov_dpp)
    return __int_as_float(__builtin_amdgcn_mov_dpp(__float_as_int(x), 0x130, 0xF, 0xF, true));
#else
    return __int_as_float(__builtin_amdgcn_update_dpp(0, __float_as_int(x), 0x130, 0xF, 0xF, true));
#endif
}

template<int KITERS>
__global__ __launch_bounds__(1024) void vin_vi_kernel(
    const float* __restrict__ obs,     // [B,64,64,3]
    const float* __restrict__ W_phi,   // [3,3]
    const float* __restrict__ b_phi,   // [3]
    float* __restrict__ feats_out)     // [B,36]
{
    const int b   = blockIdx.x;
    const int tid = threadIdx.x;
    const int w   = tid >> 6;   // wave id 0..15: rows 4w .. 4w+3
    const int l   = tid & 63;   // lane = column

    __shared__ float v_s[64 * 64];        // 16 KB (final value map, gather only)
    __shared__ float bnd[2][2][16][64];   // 16 KB: v boundary rows [buf][top/bot][wave][col]
    __shared__ float rbnd[2][16][64];     //  8 KB: rin boundary rows (static)
    __shared__ int   agent_pos;

    const float* ob = obs + (size_t)b * (4096 * 3);

    const float w00 = W_phi[0], w01 = W_phi[1], w02 = W_phi[2];
    const float w10 = W_phi[3], w11 = W_phi[4], w12 = W_phi[5];
    const float w20 = W_phi[6], w21 = W_phi[7], w22 = W_phi[8];
    const float bp0 = b_phi[0], bp1 = b_phi[1], bp2 = b_phi[2];

    float p[4], rin[4], rout[4];

    #pragma unroll
    for (int k = 0; k < 4; ++k) {
        const int cell = (4 * w + k) * 64 + l;
        const float o0 = ob[cell * 3 + 0];
        const float o1 = ob[cell * 3 + 1];
        const float o2 = ob[cell * 3 + 2];
        p[k]    = fmaxf(fmaf(o2, w20, fmaf(o1, w10, fmaf(o0, w00, bp0))), 0.f);
        rin[k]  = fmaxf(fmaf(o2, w21, fmaf(o1, w11, fmaf(o0, w01, bp1))), 0.f);
        rout[k] = fmaxf(fmaf(o2, w22, fmaf(o1, w12, fmaf(o0, w02, bp2))), 0.f);
        if (o1 > 0.5f) agent_pos = cell;   // one-hot agent: single writer
    }

    // Static rin boundary rows (rows 4w-1 / 4w+4), once.
    rbnd[0][w][l] = rin[0];
    rbnd[1][w][l] = rin[3];
    __syncthreads();
    const float rinU_b = (w > 0)  ? rbnd[1][w - 1][l] : 0.f;
    const float rinD_b = (w < 15) ? rbnd[0][w + 1][l] : 0.f;

    // aX[k] = rin(neighbor X) - rout[k]; out-of-grid terms = -rout <= 0 never
    // win the max (v >= 0 monotone, p/rin/rout >= 0, DPP zero-fill at edges).
    float aU[4], aD[4], aL[4], aR[4], v[4];
    #pragma unroll
    for (int k = 0; k < 4; ++k) {
        aU[k] = ((k > 0) ? rin[k - 1] : rinU_b) - rout[k];
        aD[k] = ((k < 3) ? rin[k + 1] : rinD_b) - rout[k];
        aL[k] = shr1(rin[k]) - rout[k];
        aR[k] = shl1(rin[k]) - rout[k];
    }

    // Iter 0 peeled: v==0 everywhere.
    #pragma unroll
    for (int k = 0; k < 4; ++k)
        v[k] = fmaxf(0.f, fmaxf(fmaxf(aU[k], aD[k]), fmaxf(aL[k], aR[k])));
    bnd[0][0][w][l] = v[0];
    bnd[0][1][w][l] = v[3];

    for (int it = 1; it < KITERS; ++it) {
        const int rd = (it - 1) & 1, wr = it & 1;
        __syncthreads();
        const float vU_b = (w > 0)  ? bnd[rd][1][w - 1][l] : 0.f;
        const float vD_b = (w < 15) ? bnd[rd][0][w + 1][l] : 0.f;

        const float ov3 = v[3];
        {   // k = 3 first (uses old v[2], vD_b); store boundary early.
            const float vk = ov3;
            const float vL = shr1(vk), vR = shl1(vk);
            const float tU = fmaf(p[3], v[2], aU[3]);
            const float tD = fmaf(p[3], vD_b, aD[3]);
            const float tL = fmaf(p[3], vL, aL[3]);
            const float tR = fmaf(p[3], vR, aR[3]);
            v[3] = fmaxf(vk, fmaxf(fmaxf(tU, tD), fmaxf(tL, tR)));
            bnd[wr][1][w][l] = v[3];
        }
        const float ov0 = v[0];
        {   // k = 0 (uses vU_b, old v[1]); store boundary early.
            const float vk = ov0;
            const float vL = shr1(vk), vR = shl1(vk);
            const float tU = fmaf(p[0], vU_b, aU[0]);
            const float tD = fmaf(p[0], v[1], aD[0]);
            const float tL = fmaf(p[0], vL, aL[0]);
            const float tR = fmaf(p[0], vR, aR[0]);
            v[0] = fmaxf(vk, fmaxf(fmaxf(tU, tD), fmaxf(tL, tR)));
            bnd[wr][0][w][l] = v[0];
        }
        // k = 1, 2: vm1 chain carries OLD previous row; k=2 uses ov3.
        float vm1 = ov0;
        #pragma unroll
        for (int k = 1; k < 3; ++k) {
            const float vk  = v[k];
            const float vp1 = (k < 2) ? v[k + 1] : ov3;
            const float vL  = shr1(vk), vR = shl1(vk);
            const float tU  = fmaf(p[k], vm1, aU[k]);
            const float tD  = fmaf(p[k], vp1, aD[k]);
            const float tL  = fmaf(p[k], vL, aL[k]);
            const float tR  = fmaf(p[k], vR, aR[k]);
            v[k] = fmaxf(vk, fmaxf(fmaxf(tU, tD), fmaxf(tL, tR)));
            vm1 = vk;
        }
    }

    #pragma unroll
    for (int k = 0; k < 4; ++k) v_s[(4 * w + k) * 64 + l] = v[k];
    __syncthreads();

    // 36 features: 3x3 zero-padded windows of (1-walls), agent, goal, v.
    if (tid < 36) {
        const int ap = agent_pos;
        const int ar = ap >> 6, ac = ap & 63;
        const int g  = tid / 9, o = tid % 9;
        const int rr = ar + o / 3 - 1;
        const int cc = ac + o % 3 - 1;
        float val = 0.f;
        if (rr >= 0 && rr < 64 && cc >= 0 && cc < 64) {
            const int cell = rr * 64 + cc;
            if      (g == 0) val = 1.f - ob[cell * 3 + 0];
            else if (g == 1) val = ob[cell * 3 + 1];
            else if (g == 2) val = ob[cell * 3 + 2];
            else             val = v_s[cell];
        }
        feats_out[b * 36 + tid] = val;
    }
}

__global__ __launch_bounds__(1024) void vin_mlp_kernel(
    const float* __restrict__ feats,   // [B,36]
    const float* __restrict__ W1,      // [36,256]
    const float* __restrict__ b1,      // [256]
    const float* __restrict__ W2,      // [256,256]
    const float* __restrict__ b2,      // [256]
    const float* __restrict__ Wl,      // [256,5]
    const float* __restrict__ bl,      // [5]
    float* __restrict__ out)           // [B,5]
{
    const int b0  = blockIdx.x * 4;    // 4 samples per block
    const int tid = threadIdx.x;
    const int c   = tid & 255;         // output column
    const int q   = tid >> 8;          // K-quarter 0..3

    __shared__ float f_s[4][36];
    __shared__ float part[4][4][256];              // [quarter][sample][col] 16KB
    __shared__ __align__(16) float h1_s[256][4];   // [col][sample] 4KB
    __shared__ __align__(16) float h2_s[4][256];   // 4KB
    __shared__ float red[16][4][5];                // 1.25KB

    if (tid < 144) f_s[tid / 36][tid % 36] = feats[b0 * 36 + tid];
    __syncthreads();

    // 36 -> 256 (linear), split-K: quarter q sums rows [9q, 9q+9)
    {
        float a0 = 0.f, a1 = 0.f, a2 = 0.f, a3 = 0.f;
        #pragma unroll
        for (int m = 0; m < 9; ++m) {
            const int i = 9 * q + m;
            const float wv = W1[i * 256 + c];
            a0 = fmaf(f_s[0][i], wv, a0);
            a1 = fmaf(f_s[1][i], wv, a1);
            a2 = fmaf(f_s[2][i], wv, a2);
            a3 = fmaf(f_s[3][i], wv, a3);
        }
        part[q][0][c] = a0; part[q][1][c] = a1;
        part[q][2][c] = a2; part[q][3][c] = a3;
    }
    __syncthreads();
    h1_s[c][q] = b1[c] + ((part[0][q][c] + part[1][q][c]) +
                          (part[2][q][c] + part[3][q][c]));
    __syncthreads();

    // 256 -> 256 (linear), split-K: quarter q sums rows [64q, 64q+64)
    {
        float a0 = 0.f, a1 = 0.f, a2 = 0.f, a3 = 0.f;
        #pragma unroll 8
        for (int m = 0; m < 64; ++m) {
            const int i = 64 * q + m;
            const float wv = W2[i * 256 + c];
            const float4 hv = *reinterpret_cast<const float4*>(&h1_s[i][0]); // bcast
            a0 = fmaf(hv.x, wv, a0);
            a1 = fmaf(hv.y, wv, a1);
            a2 = fmaf(hv.z, wv, a2);
            a3 = fmaf(hv.w, wv, a3);
        }
        part[q][0][c] = a0; part[q][1][c] = a1;
        part[q][2][c] = a2; part[q][3][c] = a3;
    }
    __syncthreads();
    h2_s[q][c] = b2[c] + ((part[0][q][c] + part[1][q][c]) +
                          (part[2][q][c] + part[3][q][c]));
    __syncthreads();

    // 256 -> 5: 320 threads, each sums a 16-wide chunk for one (sample,logit)
    if (tid < 320) {
        const int s  = tid & 3;
        const int j  = (tid >> 2) % 5;
        const int ch = tid / 20;        // 0..15
        float acc = 0.f;
        #pragma unroll
        for (int m = 0; m < 16; ++m) {
            const int i = ch * 16 + m;
            acc = fmaf(h2_s[s][i], Wl[i * 5 + j], acc);
        }
        red[ch][s][j] = acc;
    }
    __syncthreads();
    if (tid < 20) {
        const int s = tid & 3;
        const int j = tid >> 2;
        float o = bl[j];
        #pragma unroll
        for (int ch = 0; ch < 16; ++ch) o += red[ch][s][j];
        out[(b0 + s) * 5 + j] = o;
    }
}

extern "C" void kernel_launch(void* const* d_in, const int* in_sizes, int n_in,
                              void* d_out, int out_size, void* d_ws, size_t ws_size,
                              hipStream_t stream) {
    const float* obs   = (const float*)d_in[0];
    const float* W_phi = (const float*)d_in[1];
    const float* b_phi = (const float*)d_in[2];
    const float* W1    = (const float*)d_in[3];
    const float* b1    = (const float*)d_in[4];
    const float* W2    = (const float*)d_in[5];
    const float* b2    = (const float*)d_in[6];
    const float* Wl    = (const float*)d_in[7];
    const float* bl    = (const float*)d_in[8];
    float* out   = (float*)d_out;
    float* feats = (float*)d_ws;   // 1024*36*4 = 147456 bytes

    // Real pipeline.
    vin_vi_kernel<K_ITERS><<<dim3(1024), dim3(1024), 0, stream>>>(obs, W_phi, b_phi, feats);
    vin_mlp_kernel<<<dim3(256), dim3(1024), 0, stream>>>(feats, W1, b1, W2, b2, Wl, bl, out);

    // Single diagnostic of the NEW structure (dead output, deep scratch):
    // surfaces in rocprof top-5 above the ~40us harness fills.
    if (ws_size >= (64u << 20)) {
        float* dg = (float*)((char*)d_ws + (32u << 20));
        vin_vi_kernel<97><<<dim3(1024), dim3(1024), 0, stream>>>(obs, W_phi, b_phi, dg);
    }
}

// Round 9
// 118.290 us; speedup vs baseline: 1.9445x; 1.1277x over previous
//
#include <hip/hip_runtime.h>

// VIN forward — R9: codegen cleanup of the VALU-bound VI loop.
// R8: VALUBusy 98.7% but ~90 dyn VALU/wave-iter vs ~40 ideal -> per-row codegen
// bloat (suspect AGPR juggling / array codegen). This round: fully named scalar
// state (no arrays in hot loop), max3-friendly fmaxf chains (2x v_max3_f32 per
// row), padded zero-row boundary LDS (no per-iter cndmask), launch_bounds
// (1024,1) for a 128-VGPR arch budget. Structure: block=1024, 16 waves, wave w
// owns rows [4w,4w+4); lane = column; DPP wave shifts for columns.
// Diag VI<97> retained (dead output) for counters.

#define K_ITERS 10

// lane i <- lane i-1 (column l-1), lane 0 <- 0.0f  (wave_shr:1, bound_ctrl:1)
__device__ __forceinline__ float shr1(float x) {
    return __int_as_float(__builtin_amdgcn_mov_dpp(__float_as_int(x), 0x138, 0xF, 0xF, true));
}
// lane i <- lane i+1 (column l+1), lane 63 <- 0.0f  (wave_shl:1, bound_ctrl:1)
__device__ __forceinline__ float shl1(float x) {
    return __int_as_float(__builtin_amdgcn_mov_dpp(__float_as_int(x), 0x130, 0xF, 0xF, true));
}
// max3-friendly: fmaxf(fmaxf(a,b),c) -> v_max3_f32
__device__ __forceinline__ float max3(float a, float b, float c) {
    return fmaxf(fmaxf(a, b), c);
}

template<int KITERS>
__global__ __launch_bounds__(1024, 1) void vin_vi_kernel(
    const float* __restrict__ obs,     // [B,64,64,3]
    const float* __restrict__ W_phi,   // [3,3]
    const float* __restrict__ b_phi,   // [3]
    float* __restrict__ feats_out)     // [B,36]
{
    const int b   = blockIdx.x;
    const int tid = threadIdx.x;
    const int w   = tid >> 6;   // wave id 0..15: rows 4w .. 4w+3
    const int l   = tid & 63;   // lane = column

    __shared__ float v_s[64 * 64];      // 16 KB: final value map (gather only)
    __shared__ float bndU[2][17][64];   // 8.5 KB: v[3] of wave w-1 at slot [w]; slot 0 = 0
    __shared__ float bndD[2][17][64];   // 8.5 KB: v[0] of wave w+1 at slot [w+1]; slot 16 = 0
    __shared__ float rbU[17][64];       // 4.25 KB: rin row 4w-1 at [w]; slot 0 = 0
    __shared__ float rbD[17][64];       // 4.25 KB: rin row 4w+4 at [w+1]; slot 16 = 0
    __shared__ int   agent_pos;

    const float* ob = obs + (size_t)b * (4096 * 3);

    const float w00 = W_phi[0], w01 = W_phi[1], w02 = W_phi[2];
    const float w10 = W_phi[3], w11 = W_phi[4], w12 = W_phi[5];
    const float w20 = W_phi[6], w21 = W_phi[7], w22 = W_phi[8];
    const float bp0 = b_phi[0], bp1 = b_phi[1], bp2 = b_phi[2];

    // Load + phi for the 4 owned rows (named scalars).
    float p0, p1, p2, p3, ri0, ri1, ri2, ri3, ro0, ro1, ro2, ro3;
    {
        float pk[4], rik[4], rok[4];
        #pragma unroll
        for (int k = 0; k < 4; ++k) {
            const int cell = (4 * w + k) * 64 + l;
            const float o0 = ob[cell * 3 + 0];
            const float o1 = ob[cell * 3 + 1];
            const float o2 = ob[cell * 3 + 2];
            pk[k]  = fmaxf(fmaf(o2, w20, fmaf(o1, w10, fmaf(o0, w00, bp0))), 0.f);
            rik[k] = fmaxf(fmaf(o2, w21, fmaf(o1, w11, fmaf(o0, w01, bp1))), 0.f);
            rok[k] = fmaxf(fmaf(o2, w22, fmaf(o1, w12, fmaf(o0, w02, bp2))), 0.f);
            if (o1 > 0.5f) agent_pos = cell;   // one-hot agent: single writer
        }
        p0 = pk[0];  p1 = pk[1];  p2 = pk[2];  p3 = pk[3];
        ri0 = rik[0]; ri1 = rik[1]; ri2 = rik[2]; ri3 = rik[3];
        ro0 = rok[0]; ro1 = rok[1]; ro2 = rok[2]; ro3 = rok[3];
    }

    // Zero pad rows (written once, never touched again) + static rin boundaries.
    if (tid < 64) {
        bndU[0][0][l] = 0.f;  bndU[1][0][l] = 0.f;
        bndD[0][16][l] = 0.f; bndD[1][16][l] = 0.f;
        rbU[0][l] = 0.f;      rbD[16][l] = 0.f;
    }
    rbU[w + 1][l] = ri3;   // rin of my last row, for wave w+1's "up"
    rbD[w][l]     = ri0;   // rin of my first row, for wave w-1's "down"
    __syncthreads();
    const float rinU_b = rbU[w][l];
    const float rinD_b = rbD[w + 1][l];

    // Folded per-direction constants aX = rin(neighbor X) - rout.
    // Out-of-grid terms = -rout <= 0 never win (v>=0 monotone, relu >= 0,
    // DPP zero-fill at wave edges, zero pad rows vertically).
    const float aU0 = rinU_b - ro0, aU1 = ri0 - ro1, aU2 = ri1 - ro2, aU3 = ri2 - ro3;
    const float aD0 = ri1 - ro0, aD1 = ri2 - ro1, aD2 = ri3 - ro2, aD3 = rinD_b - ro3;
    const float aL0 = shr1(ri0) - ro0, aL1 = shr1(ri1) - ro1, aL2 = shr1(ri2) - ro2, aL3 = shr1(ri3) - ro3;
    const float aR0 = shl1(ri0) - ro0, aR1 = shl1(ri1) - ro1, aR2 = shl1(ri2) - ro2, aR3 = shl1(ri3) - ro3;

    // Iter 0 peeled (v == 0): v = max(0, aU, aD, aL, aR).
    float v0 = fmaxf(max3(aU0, aD0, aL0), fmaxf(aR0, 0.f));
    float v1 = fmaxf(max3(aU1, aD1, aL1), fmaxf(aR1, 0.f));
    float v2 = fmaxf(max3(aU2, aD2, aL2), fmaxf(aR2, 0.f));
    float v3 = fmaxf(max3(aU3, aD3, aL3), fmaxf(aR3, 0.f));
    bndU[0][w + 1][l] = v3;
    bndD[0][w][l]     = v0;

    for (int it = 1; it < KITERS; ++it) {
        const int rd = (it - 1) & 1, wr = it & 1;
        __syncthreads();
        const float vU_b = bndU[rd][w][l];
        const float vD_b = bndD[rd][w + 1][l];

        // Jacobi: all nv computed from OLD v0..v3, then committed.
        // Rows 1,2 first (independent of the LDS boundary reads).
        float vL, vR, m;
        vL = shr1(v1); vR = shl1(v1);
        m = max3(fmaf(p1, v0, aU1), fmaf(p1, v2, aD1), fmaf(p1, vL, aL1));
        const float nv1 = max3(m, fmaf(p1, vR, aR1), v1);

        vL = shr1(v2); vR = shl1(v2);
        m = max3(fmaf(p2, v1, aU2), fmaf(p2, v3, aD2), fmaf(p2, vL, aL2));
        const float nv2 = max3(m, fmaf(p2, vR, aR2), v2);

        vL = shr1(v3); vR = shl1(v3);
        m = max3(fmaf(p3, v2, aU3), fmaf(p3, vD_b, aD3), fmaf(p3, vL, aL3));
        const float nv3 = max3(m, fmaf(p3, vR, aR3), v3);
        bndU[wr][w + 1][l] = nv3;

        vL = shr1(v0); vR = shl1(v0);
        m = max3(fmaf(p0, vU_b, aU0), fmaf(p0, v1, aD0), fmaf(p0, vL, aL0));
        const float nv0 = max3(m, fmaf(p0, vR, aR0), v0);
        bndD[wr][w][l] = nv0;

        v0 = nv0; v1 = nv1; v2 = nv2; v3 = nv3;
    }

    v_s[(4 * w + 0) * 64 + l] = v0;
    v_s[(4 * w + 1) * 64 + l] = v1;
    v_s[(4 * w + 2) * 64 + l] = v2;
    v_s[(4 * w + 3) * 64 + l] = v3;
    __syncthreads();

    // 36 features: 3x3 zero-padded windows of (1-walls), agent, goal, v.
    if (tid < 36) {
        const int ap = agent_pos;
        const int ar = ap >> 6, ac = ap & 63;
        const int g  = tid / 9, o = tid % 9;
        const int rr = ar + o / 3 - 1;
        const int cc = ac + o % 3 - 1;
        float val = 0.f;
        if (rr >= 0 && rr < 64 && cc >= 0 && cc < 64) {
            const int cell = rr * 64 + cc;
            if      (g == 0) val = 1.f - ob[cell * 3 + 0];
            else if (g == 1) val = ob[cell * 3 + 1];
            else if (g == 2) val = ob[cell * 3 + 2];
            else             val = v_s[cell];
        }
        feats_out[b * 36 + tid] = val;
    }
}

__global__ __launch_bounds__(1024) void vin_mlp_kernel(
    const float* __restrict__ feats,   // [B,36]
    const float* __restrict__ W1,      // [36,256]
    const float* __restrict__ b1,      // [256]
    const float* __restrict__ W2,      // [256,256]
    const float* __restrict__ b2,      // [256]
    const float* __restrict__ Wl,      // [256,5]
    const float* __restrict__ bl,      // [5]
    float* __restrict__ out)           // [B,5]
{
    const int b0  = blockIdx.x * 4;    // 4 samples per block
    const int tid = threadIdx.x;
    const int c   = tid & 255;         // output column
    const int q   = tid >> 8;          // K-quarter 0..3

    __shared__ float f_s[4][36];
    __shared__ float part[4][4][256];              // [quarter][sample][col] 16KB
    __shared__ __align__(16) float h1_s[256][4];   // [col][sample] 4KB
    __shared__ __align__(16) float h2_s[4][256];   // 4KB
    __shared__ float red[16][4][5];                // 1.25KB

    if (tid < 144) f_s[tid / 36][tid % 36] = feats[b0 * 36 + tid];
    __syncthreads();

    // 36 -> 256 (linear), split-K: quarter q sums rows [9q, 9q+9)
    {
        float a0 = 0.f, a1 = 0.f, a2 = 0.f, a3 = 0.f;
        #pragma unroll
        for (int m = 0; m < 9; ++m) {
            const int i = 9 * q + m;
            const float wv = W1[i * 256 + c];
            a0 = fmaf(f_s[0][i], wv, a0);
            a1 = fmaf(f_s[1][i], wv, a1);
            a2 = fmaf(f_s[2][i], wv, a2);
            a3 = fmaf(f_s[3][i], wv, a3);
        }
        part[q][0][c] = a0; part[q][1][c] = a1;
        part[q][2][c] = a2; part[q][3][c] = a3;
    }
    __syncthreads();
    h1_s[c][q] = b1[c] + ((part[0][q][c] + part[1][q][c]) +
                          (part[2][q][c] + part[3][q][c]));
    __syncthreads();

    // 256 -> 256 (linear), split-K: quarter q sums rows [64q, 64q+64)
    {
        float a0 = 0.f, a1 = 0.f, a2 = 0.f, a3 = 0.f;
        #pragma unroll 8
        for (int m = 0; m < 64; ++m) {
            const int i = 64 * q + m;
            const float wv = W2[i * 256 + c];
            const float4 hv = *reinterpret_cast<const float4*>(&h1_s[i][0]); // bcast
            a0 = fmaf(hv.x, wv, a0);
            a1 = fmaf(hv.y, wv, a1);
            a2 = fmaf(hv.z, wv, a2);
            a3 = fmaf(hv.w, wv, a3);
        }
        part[q][0][c] = a0; part[q][1][c] = a1;
        part[q][2][c] = a2; part[q][3][c] = a3;
    }
    __syncthreads();
    h2_s[q][c] = b2[c] + ((part[0][q][c] + part[1][q][c]) +
                          (part[2][q][c] + part[3][q][c]));
    __syncthreads();

    // 256 -> 5: 320 threads, each sums a 16-wide chunk for one (sample,logit)
    if (tid < 320) {
        const int s  = tid & 3;
        const int j  = (tid >> 2) % 5;
        const int ch = tid / 20;        // 0..15
        float acc = 0.f;
        #pragma unroll
        for (int m = 0; m < 16; ++m) {
            const int i = ch * 16 + m;
            acc = fmaf(h2_s[s][i], Wl[i * 5 + j], acc);
        }
        red[ch][s][j] = acc;
    }
    __syncthreads();
    if (tid < 20) {
        const int s = tid & 3;
        const int j = tid >> 2;
        float o = bl[j];
        #pragma unroll
        for (int ch = 0; ch < 16; ++ch) o += red[ch][s][j];
        out[(b0 + s) * 5 + j] = o;
    }
}

extern "C" void kernel_launch(void* const* d_in, const int* in_sizes, int n_in,
                              void* d_out, int out_size, void* d_ws, size_t ws_size,
                              hipStream_t stream) {
    const float* obs   = (const float*)d_in[0];
    const float* W_phi = (const float*)d_in[1];
    const float* b_phi = (const float*)d_in[2];
    const float* W1    = (const float*)d_in[3];
    const float* b1    = (const float*)d_in[4];
    const float* W2    = (const float*)d_in[5];
    const float* b2    = (const float*)d_in[6];
    const float* Wl    = (const float*)d_in[7];
    const float* bl    = (const float*)d_in[8];
    float* out   = (float*)d_out;
    float* feats = (float*)d_ws;   // 1024*36*4 = 147456 bytes

    // Real pipeline.
    vin_vi_kernel<K_ITERS><<<dim3(1024), dim3(1024), 0, stream>>>(obs, W_phi, b_phi, feats);
    vin_mlp_kernel<<<dim3(256), dim3(1024), 0, stream>>>(feats, W1, b1, W2, b2, Wl, bl, out);

    // Diagnostic (dead output, deep scratch): surfaces in rocprof top-5 above
    // the ~40us harness fills; verifies the new codegen's counters.
    if (ws_size >= (64u << 20)) {
        float* dg = (float*)((char*)d_ws + (32u << 20));
        vin_vi_kernel<97><<<dim3(1024), dim3(1024), 0, stream>>>(obs, W_phi, b_phi, dg);
    }
}